// Round 5
// baseline (292.245 us; speedup 1.0000x reference)
//
#include <hip/hip_runtime.h>
#include <math.h>

// Problem dims
#define BB 512
#define DE 1024
#define DM 1024
#define NA 512
#define NP 256

typedef unsigned short ushort_t;
typedef __attribute__((ext_vector_type(8))) short s8v;   // 8 bf16 (4 VGPRs)
typedef __attribute__((ext_vector_type(4))) float f4v;   // 4 fp32 acc

static __device__ __forceinline__ float4 ld4(const float* p) {
    return *reinterpret_cast<const float4*>(p);
}

// RNE float -> bf16 bits
__device__ __forceinline__ unsigned bf16h(float x) {
    unsigned u = __float_as_uint(x);
    return (u + 0x7FFFu + ((u >> 16) & 1u)) >> 16;
}
__device__ __forceinline__ float bf16f(unsigned h) { return __uint_as_float(h << 16); }

__device__ __forceinline__ f4v mfma16(s8v a, s8v b, f4v c) {
    return __builtin_amdgcn_mfma_f32_16x16x32_bf16(a, b, c, 0, 0, 0);
}

// ================= PREP: PE table + weight/h_s hi-lo splits ===================
__device__ __forceinline__ void d_ew(const float* __restrict__ W,
                                     ushort_t* __restrict__ Hh,
                                     ushort_t* __restrict__ Hl, int bid) {
    int i = (bid * 256 + threadIdx.x) * 4;
    float4 f = ld4(W + i);
    float ff[4] = {f.x, f.y, f.z, f.w};
    unsigned h[4], l[4];
    #pragma unroll
    for (int q = 0; q < 4; ++q) { h[q] = bf16h(ff[q]); l[q] = bf16h(ff[q] - bf16f(h[q])); }
    *reinterpret_cast<uint2*>(Hh + i) = make_uint2(h[0] | (h[1] << 16), h[2] | (h[3] << 16));
    *reinterpret_cast<uint2*>(Hl + i) = make_uint2(l[0] | (l[1] << 16), l[2] | (l[3] << 16));
}

__device__ __forceinline__ void d_tr(const float* __restrict__ W,
                                     ushort_t* __restrict__ Th,
                                     ushort_t* __restrict__ Tl,
                                     int K, int N, int bid) {
    __shared__ float t[32][33];
    int ntn = N >> 5;
    int kt = bid / ntn, nt = bid - kt * ntn;
    int k0 = kt * 32, n0 = nt * 32;
    int ty = threadIdx.x >> 3, tx = (threadIdx.x & 7) * 4;
    float4 f = ld4(W + (size_t)(k0 + ty) * N + n0 + tx);
    t[ty][tx] = f.x; t[ty][tx + 1] = f.y; t[ty][tx + 2] = f.z; t[ty][tx + 3] = f.w;
    __syncthreads();
    unsigned h[4], l[4];
    #pragma unroll
    for (int q = 0; q < 4; ++q) {
        float x = t[tx + q][ty];
        h[q] = bf16h(x); l[q] = bf16h(x - bf16f(h[q]));
    }
    size_t o = (size_t)(n0 + ty) * K + k0 + tx;
    *reinterpret_cast<uint2*>(Th + o) = make_uint2(h[0] | (h[1] << 16), h[2] | (h[3] << 16));
    *reinterpret_cast<uint2*>(Tl + o) = make_uint2(l[0] | (l[1] << 16), l[2] | (l[3] << 16));
}

__global__ __launch_bounds__(256) void prep(
    const float* __restrict__ h_s, const float* __restrict__ WQo,
    const float* __restrict__ WQi, const float* __restrict__ WKo,
    const float* __restrict__ WKi, const float* __restrict__ WVi,
    const float* __restrict__ W1, const float* __restrict__ W2,
    ushort_t* peh, ushort_t* pel, ushort_t* hsh, ushort_t* hsl,
    ushort_t* WQoh, ushort_t* WQol, ushort_t* WQih, ushort_t* WQil,
    ushort_t* WKoh, ushort_t* WKol, ushort_t* WKih, ushort_t* WKil,
    ushort_t* WVih, ushort_t* WVil, ushort_t* W1th, ushort_t* W1tl,
    ushort_t* W2th, ushort_t* W2tl) {
    int bid = blockIdx.x;
    if (bid < 257) {
        int p = bid, i = threadIdx.x;
        const float c = -0.017988946039015984f; // -ln(10000)/512
        float div = expf((float)(2 * i) * c);
        float arg = (float)p * div;
        float s = sinf(arg), co = cosf(arg);
        unsigned hs = bf16h(s), hc = bf16h(co);
        unsigned ls = bf16h(s - bf16f(hs)), lc = bf16h(co - bf16f(hc));
        *reinterpret_cast<unsigned*>(peh + p * NA + 2 * i) = hs | (hc << 16);
        *reinterpret_cast<unsigned*>(pel + p * NA + 2 * i) = ls | (lc << 16);
        return;
    }
    if ((bid -= 257) < 512)  { d_ew(h_s, hsh, hsl, bid); return; }
    if ((bid -= 512) < 1024) { d_ew(WQo, WQoh, WQol, bid); return; }
    if ((bid -= 1024) < 1024){ d_ew(WQi, WQih, WQil, bid); return; }
    if ((bid -= 1024) < 512) { d_ew(WKo, WKoh, WKol, bid); return; }
    if ((bid -= 512) < 512)  { d_ew(WKi, WKih, WKil, bid); return; }
    if ((bid -= 512) < 512)  { d_ew(WVi, WVih, WVil, bid); return; }
    if ((bid -= 512) < 2048) { d_tr(W1, W1th, W1tl, DE + DM, DM, bid); return; }
    bid -= 2048;               d_tr(W2, W2th, W2tl, DM, NA, bid);
}

// ================= split-bf16 MFMA GEMM, 32x64 tile, 2-phase dbuf =============
// C[M,N] = (Ah+Al)[M,K] @ (Bh+Bl)[N,K]^T, 3-product split, fp32 accum.
// Double-buffered LDS, one barrier per K-tile, next tile's global loads issued
// before the barrier (in flight across it). Runtime per-z descriptors.
// A/B concat: k >= KS switches to A2/B2 (separate ld).
struct GD {
    const ushort_t *Ah, *Al, *A2h, *A2l;
    const ushort_t *Bh, *Bl, *B2h, *B2l;
    const float *bias;
    float *Cf; ushort_t *Ch, *Cl;
    int M, N, K, KS, lda, lda2, ldb, ldb2, ldc;
};

template<int BIAS, int RELU, int CFOUT, int CHOUT>
__global__ __launch_bounds__(256) void gemmk(GD g0, GD g1, GD g2) {
    const GD& g = blockIdx.z == 0 ? g0 : (blockIdx.z == 1 ? g1 : g2);
    const int row0 = blockIdx.y * 32, col0 = blockIdx.x * 64;
    if (row0 >= g.M || col0 >= g.N) return;

    __shared__ ushort_t sAh[2][2048], sAl[2][2048], sBh[2][4096], sBl[2][4096];
    const int tid = threadIdx.x;

    const int ar = tid >> 3, ak = (tid & 7) * 8;
    const int asi = ar * 64 + (ak ^ ((ar & 7) << 3));
    const int br = tid >> 2, bk = (tid & 3) * 16;
    const int bsw = (br & 7) << 3;
    const int bsi0 = br * 64 + (bk ^ bsw);
    const int bsi1 = br * 64 + ((bk + 8) ^ bsw);

    const int wid = tid >> 6, lane = tid & 63;
    const int wm = wid & 1, wn = wid >> 1;
    const int lm = lane & 15, lk = lane >> 4;
    const int ra = wm * 16 + lm;
    const int rb = wn * 32 + lm;
    const int aswz = (ra & 7) << 3;
    const int bswz = (rb & 7) << 3;

    const int nb = col0 + br;
    const bool bval = nb < g.N;

    int4 rah, ral, rb0h, rb1h, rb0l, rb1l;
    auto load = [&](int k0) {
        const ushort_t *aph, *apl; int ac, la;
        if (k0 >= g.KS) { aph = g.A2h; apl = g.A2l; ac = k0 - g.KS; la = g.lda2; }
        else            { aph = g.Ah;  apl = g.Al;  ac = k0;        la = g.lda; }
        size_t ao = (size_t)(row0 + ar) * la + ac + ak;
        rah = *reinterpret_cast<const int4*>(aph + ao);
        ral = *reinterpret_cast<const int4*>(apl + ao);
        const ushort_t *bph, *bpl; int bc, lb;
        if (k0 >= g.KS) { bph = g.B2h; bpl = g.B2l; bc = k0 - g.KS; lb = g.ldb2; }
        else            { bph = g.Bh;  bpl = g.Bl;  bc = k0;        lb = g.ldb; }
        if (bval) {
            size_t bo = (size_t)nb * lb + bc + bk;
            rb0h = *reinterpret_cast<const int4*>(bph + bo);
            rb1h = *reinterpret_cast<const int4*>(bph + bo + 8);
            rb0l = *reinterpret_cast<const int4*>(bpl + bo);
            rb1l = *reinterpret_cast<const int4*>(bpl + bo + 8);
        } else {
            rb0h = make_int4(0,0,0,0); rb1h = make_int4(0,0,0,0);
            rb0l = make_int4(0,0,0,0); rb1l = make_int4(0,0,0,0);
        }
    };

    f4v acc[2] = {};
    load(0);
    const int nt = g.K >> 6;
    for (int t = 0; t < nt; ++t) {
        const int c = t & 1;
        *reinterpret_cast<int4*>(&sAh[c][asi]) = rah;
        *reinterpret_cast<int4*>(&sAl[c][asi]) = ral;
        *reinterpret_cast<int4*>(&sBh[c][bsi0]) = rb0h;
        *reinterpret_cast<int4*>(&sBh[c][bsi1]) = rb1h;
        *reinterpret_cast<int4*>(&sBl[c][bsi0]) = rb0l;
        *reinterpret_cast<int4*>(&sBl[c][bsi1]) = rb1l;
        if (t + 1 < nt) load((t + 1) << 6);
        __syncthreads();
        #pragma unroll
        for (int ks = 0; ks < 2; ++ks) {
            const int ka = (ks * 32 + lk * 8) ^ aswz;
            const int kb = (ks * 32 + lk * 8) ^ bswz;
            s8v a_h = *reinterpret_cast<const s8v*>(&sAh[c][ra * 64 + ka]);
            s8v a_l = *reinterpret_cast<const s8v*>(&sAl[c][ra * 64 + ka]);
            s8v b0h = *reinterpret_cast<const s8v*>(&sBh[c][rb * 64 + kb]);
            s8v b1h = *reinterpret_cast<const s8v*>(&sBh[c][(rb + 16) * 64 + kb]);
            s8v b0l = *reinterpret_cast<const s8v*>(&sBl[c][rb * 64 + kb]);
            s8v b1l = *reinterpret_cast<const s8v*>(&sBl[c][(rb + 16) * 64 + kb]);
            acc[0] = mfma16(a_h, b0h, acc[0]);
            acc[1] = mfma16(a_h, b1h, acc[1]);
            acc[0] = mfma16(a_h, b0l, acc[0]);
            acc[1] = mfma16(a_h, b1l, acc[1]);
            acc[0] = mfma16(a_l, b0h, acc[0]);
            acc[1] = mfma16(a_l, b1h, acc[1]);
        }
        // no trailing barrier: next iter writes the other LDS buffer; the
        // barrier between its write and read separates reuse 2 iters apart.
    }

    #pragma unroll
    for (int j = 0; j < 2; ++j) {
        int gc = col0 + wn * 32 + j * 16 + lm;
        if (gc >= g.N) continue;
        float bv = BIAS ? g.bias[gc] : 0.0f;
        #pragma unroll
        for (int r = 0; r < 4; ++r) {
            int gr = row0 + wm * 16 + lk * 4 + r;
            float val = acc[j][r] + bv;
            if (RELU) val = fmaxf(val, 0.0f);
            size_t o = (size_t)gr * g.ldc + gc;
            if (CFOUT) g.Cf[o] = val;
            if (CHOUT) {
                unsigned h = bf16h(val);
                g.Ch[o] = (ushort_t)h;
                g.Cl[o] = (ushort_t)bf16h(val - bf16f(h));
            }
        }
    }
}

// ================= fused attention over phi (single HBM pass) =================
// 512 threads/block, one block per b. Scores kept in exp2 domain. Score arrays
// read back as b128 broadcasts; chunk accumulate b64 (2 cols x 8 rows/thread),
// halves combined via LDS at the end.
__global__ __launch_bounds__(512) void phi_attn(
    const float* __restrict__ phi, const float* __restrict__ U,
    const float* __restrict__ po, const float* __restrict__ pi,
    float* __restrict__ v, ushort_t* __restrict__ wh, ushort_t* __restrict__ wl) {
    __shared__ float chunk[16 * 512];   // 32 KB (reused as exchange buffer)
    __shared__ float4 sco4[2][4], sci4[2][4];
    __shared__ float sred[8];
    const int b = blockIdx.x, tid = threadIdx.x;
    const int wave = tid >> 6, lane = tid & 63;
    const int cp = tid & 255, rh = tid >> 8;
    const float sc = 0.03125f * 1.4426950408889634f;  // 1/sqrt(dm) * log2(e)

    const float* uo = U + (size_t)b * 1024;
    const float* ui = uo + 512;
    float4 uo0 = ld4(uo + lane * 8), uo1 = ld4(uo + lane * 8 + 4);
    float4 ui0 = ld4(ui + lane * 8), ui1 = ld4(ui + lane * 8 + 4);
    const float* pb = phi + (size_t)b * NP * NA;

    float4 x00, x01, x10, x11;
    {
        const float* r0 = pb + (size_t)(wave * 2) * NA + lane * 8;
        x00 = ld4(r0); x01 = ld4(r0 + 4);
        x10 = ld4(r0 + NA); x11 = ld4(r0 + NA + 4);
    }

    float mo = -3.0e38f, mi = -3.0e38f;
    float Zo = 0.f, Zi = 0.f;
    float2 va = {0.f, 0.f}, Sa = {0.f, 0.f};

    for (int c = 0; c < 16; ++c) {
        const int p = c & 1;
        // ---- score 2 rows from regs ----
        {
            float d0a = uo0.x*x00.x + uo0.y*x00.y + uo0.z*x00.z + uo0.w*x00.w
                      + uo1.x*x01.x + uo1.y*x01.y + uo1.z*x01.z + uo1.w*x01.w;
            float d1a = ui0.x*x00.x + ui0.y*x00.y + ui0.z*x00.z + ui0.w*x00.w
                      + ui1.x*x01.x + ui1.y*x01.y + ui1.z*x01.z + ui1.w*x01.w;
            float d0b = uo0.x*x10.x + uo0.y*x10.y + uo0.z*x10.z + uo0.w*x10.w
                      + uo1.x*x11.x + uo1.y*x11.y + uo1.z*x11.z + uo1.w*x11.w;
            float d1b = ui0.x*x10.x + ui0.y*x10.y + ui0.z*x10.z + ui0.w*x10.w
                      + ui1.x*x11.x + ui1.y*x11.y + ui1.z*x11.z + ui1.w*x11.w;
            for (int off = 32; off; off >>= 1) {
                d0a += __shfl_xor(d0a, off); d1a += __shfl_xor(d1a, off);
                d0b += __shfl_xor(d0b, off); d1b += __shfl_xor(d1b, off);
            }
            if (lane == 0) {
                int n0 = c * 16 + wave * 2;
                float* so = reinterpret_cast<float*>(&sco4[p][0]);
                float* si = reinterpret_cast<float*>(&sci4[p][0]);
                so[wave*2]     = (d0a + po[b * NP + n0]) * sc;
                si[wave*2]     = (d1a + pi[b * 257 + n0 + 1]) * sc;
                so[wave*2 + 1] = (d0b + po[b * NP + n0 + 1]) * sc;
                si[wave*2 + 1] = (d1b + pi[b * 257 + n0 + 2]) * sc;
            }
        }
        __syncthreads();   // prev accumulate done; safe to overwrite chunk
        // ---- ds_write chunk ----
        {
            float* c0 = &chunk[(wave * 2) * 512 + lane * 8];
            *reinterpret_cast<float4*>(c0) = x00;
            *reinterpret_cast<float4*>(c0 + 4) = x01;
            *reinterpret_cast<float4*>(c0 + 512) = x10;
            *reinterpret_cast<float4*>(c0 + 516) = x11;
        }
        // ---- prefetch next chunk (in flight across barrier) ----
        if (c + 1 < 16) {
            const float* r0 = pb + (size_t)((c + 1) * 16 + wave * 2) * NA + lane * 8;
            x00 = ld4(r0); x01 = ld4(r0 + 4);
            x10 = ld4(r0 + NA); x11 = ld4(r0 + NA + 4);
        }
        __syncthreads();   // chunk + scores visible
        // ---- read scores as b128 broadcasts into regs ----
        float so[16], si[16];
        #pragma unroll
        for (int q = 0; q < 4; ++q) {
            float4 a = sco4[p][q];
            so[q*4] = a.x; so[q*4+1] = a.y; so[q*4+2] = a.z; so[q*4+3] = a.w;
            float4 e = sci4[p][q];
            si[q*4] = e.x; si[q*4+1] = e.y; si[q*4+2] = e.z; si[q*4+3] = e.w;
        }
        float nmo = mo, nmi = mi;
        #pragma unroll
        for (int n = 0; n < 16; ++n) {
            nmo = fmaxf(nmo, so[n]); nmi = fmaxf(nmi, si[n]);
        }
        float fo = exp2f(mo - nmo), fi = exp2f(mi - nmi);
        va.x *= fo; va.y *= fo; Zo *= fo;
        Sa.x *= fi; Sa.y *= fi; Zi *= fi;
        mo = nmo; mi = nmi;
        // ---- accumulate: 8 rows (this half) x 2 cols ----
        #pragma unroll
        for (int n = 0; n < 8; ++n) {
            int rr = rh * 8 + n;
            float e0 = exp2f(so[rr] - mo);
            float e1 = exp2f(si[rr] - mi);
            float2 x = *reinterpret_cast<float2*>(&chunk[rr * 512 + cp * 2]);
            va.x = fmaf(e0, x.x, va.x); va.y = fmaf(e0, x.y, va.y);
            Sa.x = fmaf(e1, x.x, Sa.x); Sa.y = fmaf(e1, x.y, Sa.y);
            Zo += e0; Zi += e1;
        }
    }

    // ---- combine row-halves via LDS exchange ----
    __syncthreads();
    float* fs = chunk;
    *reinterpret_cast<float2*>(&fs[2 * tid]) = va;
    *reinterpret_cast<float2*>(&fs[1024 + 2 * tid]) = Sa;
    fs[2048 + tid] = Zo; fs[3072 + tid] = Zi;
    __syncthreads();
    {
        float2 t1 = *reinterpret_cast<float2*>(&fs[2 * (tid ^ 256)]);
        va.x += t1.x; va.y += t1.y;
        float2 t2 = *reinterpret_cast<float2*>(&fs[1024 + 2 * (tid ^ 256)]);
        Sa.x += t2.x; Sa.y += t2.y;
        Zo += fs[2048 + (tid ^ 256)];
        Zi += fs[3072 + (tid ^ 256)];
    }

    float iZo = 1.0f / Zo;
    float2 v2 = {va.x * iZo, va.y * iZo};
    float2 ui2 = *reinterpret_cast<const float2*>(&ui[cp * 2]);
    float part = (rh == 0) ? (ui2.x * v2.x + ui2.y * v2.y) : 0.f;
    for (int off = 32; off; off >>= 1) part += __shfl_xor(part, off);
    if (lane == 0) sred[wave] = part;
    __syncthreads();
    float dot = ((sred[0] + sred[1]) + (sred[2] + sred[3]))
              + ((sred[4] + sred[5]) + (sred[6] + sred[7]));
    float s0 = (dot + pi[b * 257]) * sc;
    float e0 = exp2f(s0 - mi);
    float iZ = 1.0f / (Zi + e0);
    float wx = (e0 * v2.x + Sa.x) * iZ;
    float wy = (e0 * v2.y + Sa.y) * iZ;
    if (rh == 0) {
        *reinterpret_cast<float2*>(&v[(size_t)b * NA + cp * 2]) = v2;
        unsigned hx = bf16h(wx), hy = bf16h(wy);
        *reinterpret_cast<unsigned*>(wh + (size_t)b * NA + cp * 2) = hx | (hy << 16);
        unsigned lx = bf16h(wx - bf16f(hx)), ly = bf16h(wy - bf16f(hy));
        *reinterpret_cast<unsigned*>(wl + (size_t)b * NA + cp * 2) = lx | (ly << 16);
    }
}

// ---------------- final: out = softmax(v + logits) ----------------------------
__global__ __launch_bounds__(256) void final_softmax(const float* __restrict__ v,
                                                     float* __restrict__ out) {
    __shared__ float smem[4];
    int b = blockIdx.x, t = threadIdx.x;
    int lane = t & 63, w = t >> 6;
    float z0 = out[(size_t)b * NA + t] + v[(size_t)b * NA + t];
    float z1 = out[(size_t)b * NA + 256 + t] + v[(size_t)b * NA + 256 + t];
    float m = fmaxf(z0, z1);
    for (int off = 32; off; off >>= 1) m = fmaxf(m, __shfl_xor(m, off));
    __syncthreads();
    if (lane == 0) smem[w] = m;
    __syncthreads();
    m = fmaxf(fmaxf(smem[0], smem[1]), fmaxf(smem[2], smem[3]));
    float e0 = expf(z0 - m), e1 = expf(z1 - m);
    float s = e0 + e1;
    for (int off = 32; off; off >>= 1) s += __shfl_xor(s, off);
    __syncthreads();
    if (lane == 0) smem[w] = s;
    __syncthreads();
    float Z = (smem[0] + smem[1]) + (smem[2] + smem[3]);
    out[(size_t)b * NA + t] = e0 / Z;
    out[(size_t)b * NA + 256 + t] = e1 / Z;
}

// ---------------- launch ------------------------------------------------------
extern "C" void kernel_launch(void* const* d_in, const int* in_sizes, int n_in,
                              void* d_out, int out_size, void* d_ws, size_t ws_size,
                              hipStream_t stream) {
    const float* h_s = (const float*)d_in[0];
    const float* phi = (const float*)d_in[1];
    const float* WQo = (const float*)d_in[2];
    const float* WKo = (const float*)d_in[3];
    const float* WQi = (const float*)d_in[4];
    const float* WKi = (const float*)d_in[5];
    const float* WVi = (const float*)d_in[6];
    const float* W1  = (const float*)d_in[7];
    const float* b1  = (const float*)d_in[8];
    const float* W2  = (const float*)d_in[9];
    const float* b2  = (const float*)d_in[10];
    float* out = (float*)d_out;
    float* wsf = (float*)d_ws;

    size_t off = 0;
    auto af = [&](size_t n) { float* p = wsf + off; off += (n + 3) & ~(size_t)3; return p; };
    auto au = [&](size_t n) { ushort_t* p = (ushort_t*)(wsf + off); off += ((n / 2) + 3) & ~(size_t)3; return p; };

    // bf16 hi/lo buffers
    ushort_t* peh   = au(257 * NA);          ushort_t* pel   = au(257 * NA);
    ushort_t* hsh   = au((size_t)BB*DE);     ushort_t* hsl   = au((size_t)BB*DE);
    ushort_t* WQoh  = au((size_t)DE*DM);     ushort_t* WQol  = au((size_t)DE*DM);
    ushort_t* WQih  = au((size_t)DE*DM);     ushort_t* WQil  = au((size_t)DE*DM);
    ushort_t* WKoh  = au((size_t)NA*DM);     ushort_t* WKol  = au((size_t)NA*DM);
    ushort_t* WKih  = au((size_t)NA*DM);     ushort_t* WKil  = au((size_t)NA*DM);
    ushort_t* WVih  = au((size_t)NA*DM);     ushort_t* WVil  = au((size_t)NA*DM);
    ushort_t* W1th  = au((size_t)DM*(DE+DM));ushort_t* W1tl  = au((size_t)DM*(DE+DM));
    ushort_t* W2th  = au((size_t)NA*DM);     ushort_t* W2tl  = au((size_t)NA*DM);
    // weight products
    ushort_t* Wbigh = au((size_t)1024*DE);   ushort_t* Wbigl = au((size_t)1024*DE);
    ushort_t* Wv1th = au((size_t)DM*NA);     ushort_t* Wv1tl = au((size_t)DM*NA);
    // activations
    float*    Ubig  = af((size_t)BB * 1024);
    ushort_t* Ubigh = au((size_t)BB*1024);   ushort_t* Ubigl = au((size_t)BB*1024);
    float*    po    = af((size_t)BB * NP);
    float*    pi    = af((size_t)BB * 257);
    float*    v     = af((size_t)BB * NA);
    ushort_t* wh    = au((size_t)BB*NA);     ushort_t* wl    = au((size_t)BB*NA);
    ushort_t* hidh  = au((size_t)BB*DM);     ushort_t* hidl  = au((size_t)BB*DM);

    // 1. prep
    prep<<<6913, 256, 0, stream>>>(h_s, WQo, WQi, WKo, WKi, WVi, W1, W2,
                                   peh, pel, hsh, hsl,
                                   WQoh, WQol, WQih, WQil,
                                   WKoh, WKol, WKih, WKil,
                                   WVih, WVil, W1th, W1tl, W2th, W2tl);

    auto mk = [](const ushort_t* Ah, const ushort_t* Al,
                 const ushort_t* A2h, const ushort_t* A2l,
                 const ushort_t* Bh, const ushort_t* Bl,
                 const ushort_t* B2h, const ushort_t* B2l,
                 const float* bias, float* Cf, ushort_t* Ch, ushort_t* Cl,
                 int M, int N, int K, int KS,
                 int lda, int lda2, int ldb, int ldb2, int ldc) -> GD {
        GD g; g.Ah=Ah; g.Al=Al; g.A2h=A2h; g.A2l=A2l;
        g.Bh=Bh; g.Bl=Bl; g.B2h=B2h; g.B2l=B2l; g.bias=bias;
        g.Cf=Cf; g.Ch=Ch; g.Cl=Cl; g.M=M; g.N=N; g.K=K; g.KS=KS;
        g.lda=lda; g.lda2=lda2; g.ldb=ldb; g.ldb2=ldb2; g.ldc=ldc; return g;
    };

    // 2. weight batch: Wco, Wci (-> Wbig rows 0-511 / 512-1023), Wv1t
    {
        GD z0 = mk(WKoh, WKol, 0,0, WQoh, WQol, 0,0, nullptr,
                   nullptr, Wbigh, Wbigl, 512, 1024, 1024, 1024,
                   1024, 0, 1024, 0, 1024);
        GD z1 = mk(WKih, WKil, 0,0, WQih, WQil, 0,0, nullptr,
                   nullptr, Wbigh + (size_t)512*1024, Wbigl + (size_t)512*1024,
                   512, 1024, 1024, 1024, 1024, 0, 1024, 0, 1024);
        GD z2 = mk(W1th + 1024, W1tl + 1024, 0,0, WVih, WVil, 0,0, nullptr,
                   nullptr, Wv1th, Wv1tl, 1024, 512, 1024, 1024,
                   2048, 0, 1024, 0, 512);
        gemmk<0,0,0,1><<<dim3(16, 32, 3), 256, 0, stream>>>(z0, z1, z2);
    }

    // 3. U = h_s @ Wbig^T  (cols 0-511 u_out, 512-1023 u_in), fp32 + hi/lo
    {
        GD z = mk(hsh, hsl, 0,0, Wbigh, Wbigl, 0,0, nullptr,
                  Ubig, Ubigh, Ubigl, 512, 1024, 1024, 1024,
                  1024, 0, 1024, 0, 1024);
        gemmk<0,0,1,1><<<dim3(16, 16, 1), 256, 0, stream>>>(z, z, z);
    }

    // 4. pe dots: po = u_out@pe[0:256]^T, pi = u_in@pe[0:257]^T
    {
        GD z0 = mk(Ubigh, Ubigl, 0,0, peh, pel, 0,0, nullptr,
                   po, nullptr, nullptr, 512, 256, 512, 512,
                   1024, 0, 512, 0, 256);
        GD z1 = mk(Ubigh + 512, Ubigl + 512, 0,0, peh, pel, 0,0, nullptr,
                   pi, nullptr, nullptr, 512, 257, 512, 512,
                   1024, 0, 512, 0, 257);
        gemmk<0,0,1,0><<<dim3(5, 16, 2), 256, 0, stream>>>(z0, z1, z1);
    }

    // 5. fused attention over phi -> v (fp32), w (hi/lo)
    phi_attn<<<BB, 512, 0, stream>>>(phi, Ubig, po, pi, v, wh, wl);

    // 6. hidden = relu([h_s|w] @ [W1a^T|Wv1t]^T + b1) -> hi/lo
    {
        GD z = mk(hsh, hsl, wh, wl, W1th, W1tl, Wv1th, Wv1tl, b1,
                  nullptr, hidh, hidl, 512, 1024, 1536, 1024,
                  1024, 512, 2048, 512, 1024);
        gemmk<1,1,0,1><<<dim3(16, 16, 1), 256, 0, stream>>>(z, z, z);
    }

    // 7. logits = hidden @ W2 + b2 -> out (fp32)
    {
        GD z = mk(hidh, hidl, 0,0, W2th, W2tl, 0,0, b2,
                  out, nullptr, nullptr, 512, 512, 1024, 1024,
                  1024, 0, 1024, 0, 512);
        gemmk<1,0,1,0><<<dim3(8, 16, 1), 256, 0, stream>>>(z, z, z);
    }

    // 8. out = softmax(v + logits)
    final_softmax<<<BB, 256, 0, stream>>>(v, out);
}

// Round 6
// 170.990 us; speedup vs baseline: 1.7091x; 1.7091x over previous
//
#include <hip/hip_runtime.h>
#include <math.h>

// Problem dims
#define BB 512
#define DE 1024
#define DM 1024
#define NA 512
#define NP 256

typedef unsigned short ushort_t;
typedef __attribute__((ext_vector_type(8))) short s8v;   // 8 bf16 (4 VGPRs)
typedef __attribute__((ext_vector_type(4))) float f4v;   // 4 fp32 acc

static __device__ __forceinline__ float4 ld4(const float* p) {
    return *reinterpret_cast<const float4*>(p);
}

// RNE float -> bf16 bits
__device__ __forceinline__ unsigned bf16h(float x) {
    unsigned u = __float_as_uint(x);
    return (u + 0x7FFFu + ((u >> 16) & 1u)) >> 16;
}
__device__ __forceinline__ float bf16f(unsigned h) { return __uint_as_float(h << 16); }

__device__ __forceinline__ f4v mfma16(s8v a, s8v b, f4v c) {
    return __builtin_amdgcn_mfma_f32_16x16x32_bf16(a, b, c, 0, 0, 0);
}

// ================= PREP: PE table + weight/h_s hi-lo splits ===================
__device__ __forceinline__ void d_ew(const float* __restrict__ W,
                                     ushort_t* __restrict__ Hh,
                                     ushort_t* __restrict__ Hl, int bid) {
    int i = (bid * 256 + threadIdx.x) * 4;
    float4 f = ld4(W + i);
    float ff[4] = {f.x, f.y, f.z, f.w};
    unsigned h[4], l[4];
    #pragma unroll
    for (int q = 0; q < 4; ++q) { h[q] = bf16h(ff[q]); l[q] = bf16h(ff[q] - bf16f(h[q])); }
    *reinterpret_cast<uint2*>(Hh + i) = make_uint2(h[0] | (h[1] << 16), h[2] | (h[3] << 16));
    *reinterpret_cast<uint2*>(Hl + i) = make_uint2(l[0] | (l[1] << 16), l[2] | (l[3] << 16));
}

__device__ __forceinline__ void d_tr(const float* __restrict__ W,
                                     ushort_t* __restrict__ Th,
                                     ushort_t* __restrict__ Tl,
                                     int K, int N, int bid) {
    __shared__ float t[32][33];
    int ntn = N >> 5;
    int kt = bid / ntn, nt = bid - kt * ntn;
    int k0 = kt * 32, n0 = nt * 32;
    int ty = threadIdx.x >> 3, tx = (threadIdx.x & 7) * 4;
    float4 f = ld4(W + (size_t)(k0 + ty) * N + n0 + tx);
    t[ty][tx] = f.x; t[ty][tx + 1] = f.y; t[ty][tx + 2] = f.z; t[ty][tx + 3] = f.w;
    __syncthreads();
    unsigned h[4], l[4];
    #pragma unroll
    for (int q = 0; q < 4; ++q) {
        float x = t[tx + q][ty];
        h[q] = bf16h(x); l[q] = bf16h(x - bf16f(h[q]));
    }
    size_t o = (size_t)(n0 + ty) * K + k0 + tx;
    *reinterpret_cast<uint2*>(Th + o) = make_uint2(h[0] | (h[1] << 16), h[2] | (h[3] << 16));
    *reinterpret_cast<uint2*>(Tl + o) = make_uint2(l[0] | (l[1] << 16), l[2] | (l[3] << 16));
}

__global__ __launch_bounds__(256) void prep(
    const float* __restrict__ h_s, const float* __restrict__ WQo,
    const float* __restrict__ WQi, const float* __restrict__ WKo,
    const float* __restrict__ WKi, const float* __restrict__ WVi,
    const float* __restrict__ W1, const float* __restrict__ W2,
    ushort_t* peh, ushort_t* pel, ushort_t* hsh, ushort_t* hsl,
    ushort_t* WQoh, ushort_t* WQol, ushort_t* WQih, ushort_t* WQil,
    ushort_t* WKoh, ushort_t* WKol, ushort_t* WKih, ushort_t* WKil,
    ushort_t* WVih, ushort_t* WVil, ushort_t* W1th, ushort_t* W1tl,
    ushort_t* W2th, ushort_t* W2tl) {
    int bid = blockIdx.x;
    if (bid < 257) {
        int p = bid, i = threadIdx.x;
        const float c = -0.017988946039015984f; // -ln(10000)/512
        float div = expf((float)(2 * i) * c);
        float arg = (float)p * div;
        float s = sinf(arg), co = cosf(arg);
        unsigned hs = bf16h(s), hc = bf16h(co);
        unsigned ls = bf16h(s - bf16f(hs)), lc = bf16h(co - bf16f(hc));
        *reinterpret_cast<unsigned*>(peh + p * NA + 2 * i) = hs | (hc << 16);
        *reinterpret_cast<unsigned*>(pel + p * NA + 2 * i) = ls | (lc << 16);
        return;
    }
    if ((bid -= 257) < 512)  { d_ew(h_s, hsh, hsl, bid); return; }
    if ((bid -= 512) < 1024) { d_ew(WQo, WQoh, WQol, bid); return; }
    if ((bid -= 1024) < 1024){ d_ew(WQi, WQih, WQil, bid); return; }
    if ((bid -= 1024) < 512) { d_ew(WKo, WKoh, WKol, bid); return; }
    if ((bid -= 512) < 512)  { d_ew(WKi, WKih, WKil, bid); return; }
    if ((bid -= 512) < 512)  { d_ew(WVi, WVih, WVil, bid); return; }
    if ((bid -= 512) < 2048) { d_tr(W1, W1th, W1tl, DE + DM, DM, bid); return; }
    bid -= 2048;               d_tr(W2, W2th, W2tl, DM, NA, bid);
}

// ================= split-bf16 MFMA GEMM tile (all-static dims) ================
// C[M,N] = (Ah+Al)[M,K] @ (Bh+Bl)[N,K]^T, 3-product split, fp32 accum.
// 32x64 tile, 4 waves, static double-buffered LDS, ONE barrier per K-tile,
// next tile's global loads issued before the barrier. Fully unrolled (K static).
// Concat: k >= KS reads A2 (stride LDA2) / B2 (stride LDB2).
template<int M, int N, int K, int KS, int LDA, int LDA2, int LDB, int LDB2,
         int LDC, int BIAS, int RELU, int CFOUT, int CHOUT>
__device__ __forceinline__ void gtile(
    const ushort_t* __restrict__ Ah, const ushort_t* __restrict__ Al,
    const ushort_t* __restrict__ A2h, const ushort_t* __restrict__ A2l,
    const ushort_t* __restrict__ Bh, const ushort_t* __restrict__ Bl,
    const ushort_t* __restrict__ B2h, const ushort_t* __restrict__ B2l,
    const float* __restrict__ bias, float* __restrict__ Cf,
    ushort_t* __restrict__ Ch, ushort_t* __restrict__ Cl,
    ushort_t* sAh, ushort_t* sAl, ushort_t* sBh, ushort_t* sBl) {
    const int row0 = blockIdx.y * 32, col0 = blockIdx.x * 64;
    if (row0 >= M || col0 >= N) return;
    const int tid = threadIdx.x;

    const int ar = tid >> 3, ak = (tid & 7) * 8;
    const int asi = ar * 64 + (ak ^ ((ar & 7) << 3));
    const int br = tid >> 2, bk = (tid & 3) * 16;
    const int bsw = (br & 7) << 3;
    const int bsi0 = br * 64 + (bk ^ bsw);
    const int bsi1 = br * 64 + ((bk + 8) ^ bsw);

    const int wid = tid >> 6, lane = tid & 63;
    const int wm = wid & 1, wn = wid >> 1;
    const int lm = lane & 15, lk = lane >> 4;
    const int ra = wm * 16 + lm;
    const int rb = wn * 32 + lm;
    const int aswz = (ra & 7) << 3;
    const int bswz = (rb & 7) << 3;

    const int nb = col0 + br;
    const bool bval = (N % 64 == 0) || (nb < N);

    int4 rah, ral, rb0h, rb1h, rb0l, rb1l;
    auto load = [&](int k0) {
        if (KS < K && k0 >= KS) {
            size_t ao = (size_t)(row0 + ar) * LDA2 + (k0 - KS) + ak;
            rah = *reinterpret_cast<const int4*>(A2h + ao);
            ral = *reinterpret_cast<const int4*>(A2l + ao);
        } else {
            size_t ao = (size_t)(row0 + ar) * LDA + k0 + ak;
            rah = *reinterpret_cast<const int4*>(Ah + ao);
            ral = *reinterpret_cast<const int4*>(Al + ao);
        }
        if (bval) {
            if (KS < K && k0 >= KS) {
                size_t bo = (size_t)nb * LDB2 + (k0 - KS) + bk;
                rb0h = *reinterpret_cast<const int4*>(B2h + bo);
                rb1h = *reinterpret_cast<const int4*>(B2h + bo + 8);
                rb0l = *reinterpret_cast<const int4*>(B2l + bo);
                rb1l = *reinterpret_cast<const int4*>(B2l + bo + 8);
            } else {
                size_t bo = (size_t)nb * LDB + k0 + bk;
                rb0h = *reinterpret_cast<const int4*>(Bh + bo);
                rb1h = *reinterpret_cast<const int4*>(Bh + bo + 8);
                rb0l = *reinterpret_cast<const int4*>(Bl + bo);
                rb1l = *reinterpret_cast<const int4*>(Bl + bo + 8);
            }
        } else {
            rb0h = make_int4(0,0,0,0); rb1h = make_int4(0,0,0,0);
            rb0l = make_int4(0,0,0,0); rb1l = make_int4(0,0,0,0);
        }
    };

    f4v acc[2] = {};
    load(0);
    constexpr int NT = K >> 6;
    #pragma unroll
    for (int t = 0; t < NT; ++t) {
        const int co = (t & 1) ? 2048 : 0;
        const int cb = (t & 1) ? 4096 : 0;
        *reinterpret_cast<int4*>(&sAh[co + asi]) = rah;
        *reinterpret_cast<int4*>(&sAl[co + asi]) = ral;
        *reinterpret_cast<int4*>(&sBh[cb + bsi0]) = rb0h;
        *reinterpret_cast<int4*>(&sBh[cb + bsi1]) = rb1h;
        *reinterpret_cast<int4*>(&sBl[cb + bsi0]) = rb0l;
        *reinterpret_cast<int4*>(&sBl[cb + bsi1]) = rb1l;
        if (t + 1 < NT) load((t + 1) << 6);
        __syncthreads();
        #pragma unroll
        for (int ks = 0; ks < 2; ++ks) {
            const int ka = (ks * 32 + lk * 8) ^ aswz;
            const int kb = (ks * 32 + lk * 8) ^ bswz;
            s8v a_h = *reinterpret_cast<const s8v*>(&sAh[co + ra * 64 + ka]);
            s8v a_l = *reinterpret_cast<const s8v*>(&sAl[co + ra * 64 + ka]);
            s8v b0h = *reinterpret_cast<const s8v*>(&sBh[cb + rb * 64 + kb]);
            s8v b1h = *reinterpret_cast<const s8v*>(&sBh[cb + (rb + 16) * 64 + kb]);
            s8v b0l = *reinterpret_cast<const s8v*>(&sBl[cb + rb * 64 + kb]);
            s8v b1l = *reinterpret_cast<const s8v*>(&sBl[cb + (rb + 16) * 64 + kb]);
            acc[0] = mfma16(a_h, b0h, acc[0]);
            acc[1] = mfma16(a_h, b1h, acc[1]);
            acc[0] = mfma16(a_h, b0l, acc[0]);
            acc[1] = mfma16(a_h, b1l, acc[1]);
            acc[0] = mfma16(a_l, b0h, acc[0]);
            acc[1] = mfma16(a_l, b1h, acc[1]);
        }
        // single barrier per tile: next iter writes the OTHER buffer; writes to
        // THIS buffer (t+2) are gated by the next barrier (lgkm drained there).
    }

    #pragma unroll
    for (int j = 0; j < 2; ++j) {
        int gc = col0 + wn * 32 + j * 16 + lm;
        if (N % 64 != 0 && gc >= N) continue;
        float bv = BIAS ? bias[gc] : 0.0f;
        #pragma unroll
        for (int r = 0; r < 4; ++r) {
            int gr = row0 + wm * 16 + lk * 4 + r;
            float val = acc[j][r] + bv;
            if (RELU) val = fmaxf(val, 0.0f);
            size_t o = (size_t)gr * LDC + gc;
            if (CFOUT) Cf[o] = val;
            if (CHOUT) {
                unsigned h = bf16h(val);
                Ch[o] = (ushort_t)h;
                Cl[o] = (ushort_t)bf16h(val - bf16f(h));
            }
        }
    }
}

#define GSHARED \
    __shared__ ushort_t sAh[2 * 2048], sAl[2 * 2048]; \
    __shared__ ushort_t sBh[2 * 4096], sBl[2 * 4096];

// ---- weight batch: z0/z1: Wc = WK @ WQ^T (512x1024x1024); z2: Wv1t ----------
__global__ __launch_bounds__(256) void wbatch(
    const ushort_t* WKoh, const ushort_t* WKol,
    const ushort_t* WKih, const ushort_t* WKil,
    const ushort_t* WQoh, const ushort_t* WQol,
    const ushort_t* WQih, const ushort_t* WQil,
    const ushort_t* W1th, const ushort_t* W1tl,
    const ushort_t* WVih, const ushort_t* WVil,
    ushort_t* Wbigh, ushort_t* Wbigl,
    ushort_t* Wv1th, ushort_t* Wv1tl) {
    GSHARED
    const int z = blockIdx.z;
    if (z == 2) {
        // Wv1t[n][a] = sum_d W1b[d][n] * WVi[a][d]  (M=1024,N=512,K=1024)
        gtile<1024, 512, 1024, 1024, 2048, 1, 1024, 1, 512, 0,0,0,1>(
            W1th + 1024, W1tl + 1024, nullptr, nullptr,
            WVih, WVil, nullptr, nullptr,
            nullptr, nullptr, Wv1th, Wv1tl, sAh, sAl, sBh, sBl);
    } else {
        const ushort_t* Ah = z ? WKih : WKoh;
        const ushort_t* Al = z ? WKil : WKol;
        const ushort_t* Bh = z ? WQih : WQoh;
        const ushort_t* Bl = z ? WQil : WQol;
        ushort_t* Ch = Wbigh + (size_t)z * 512 * 1024;
        ushort_t* Cl = Wbigl + (size_t)z * 512 * 1024;
        gtile<512, 1024, 1024, 1024, 1024, 1, 1024, 1, 1024, 0,0,0,1>(
            Ah, Al, nullptr, nullptr, Bh, Bl, nullptr, nullptr,
            nullptr, nullptr, Ch, Cl, sAh, sAl, sBh, sBl);
    }
}

// ---- U = h_s @ Wbig^T (512x1024x1024), fp32 + hi/lo --------------------------
__global__ __launch_bounds__(256) void ugemm(
    const ushort_t* hsh, const ushort_t* hsl,
    const ushort_t* Wbigh, const ushort_t* Wbigl,
    float* Ubig, ushort_t* Ubigh, ushort_t* Ubigl) {
    GSHARED
    gtile<512, 1024, 1024, 1024, 1024, 1, 1024, 1, 1024, 0,0,1,1>(
        hsh, hsl, nullptr, nullptr, Wbigh, Wbigl, nullptr, nullptr,
        nullptr, Ubig, Ubigh, Ubigl, sAh, sAl, sBh, sBl);
}

// ---- pe dots: z0: po = u_out@pe[0:256]^T; z1: pi = u_in@pe[0:257]^T ----------
__global__ __launch_bounds__(256) void pedots(
    const ushort_t* Ubigh, const ushort_t* Ubigl,
    const ushort_t* peh, const ushort_t* pel,
    float* po, float* pi) {
    GSHARED
    if (blockIdx.z == 0) {
        gtile<512, 256, 512, 512, 1024, 1, 512, 1, 256, 0,0,1,0>(
            Ubigh, Ubigl, nullptr, nullptr, peh, pel, nullptr, nullptr,
            nullptr, po, nullptr, nullptr, sAh, sAl, sBh, sBl);
    } else {
        gtile<512, 257, 512, 512, 1024, 1, 512, 1, 257, 0,0,1,0>(
            Ubigh + 512, Ubigl + 512, nullptr, nullptr, peh, pel, nullptr, nullptr,
            nullptr, pi, nullptr, nullptr, sAh, sAl, sBh, sBl);
    }
}

// ---- hidden = relu([h_s|w] @ [W1a^T|Wv1t]^T + b1) (512x1024x1536) ------------
__global__ __launch_bounds__(256) void hgemm(
    const ushort_t* hsh, const ushort_t* hsl,
    const ushort_t* wh, const ushort_t* wl,
    const ushort_t* W1th, const ushort_t* W1tl,
    const ushort_t* Wv1th, const ushort_t* Wv1tl,
    const float* b1, ushort_t* hidh, ushort_t* hidl) {
    GSHARED
    gtile<512, 1024, 1536, 1024, 1024, 512, 2048, 512, 1024, 1,1,0,1>(
        hsh, hsl, wh, wl, W1th, W1tl, Wv1th, Wv1tl,
        b1, nullptr, hidh, hidl, sAh, sAl, sBh, sBl);
}

// ---- logits = hidden @ W2 + b2 (512x512x1024) -> out -------------------------
__global__ __launch_bounds__(256) void lgemm(
    const ushort_t* hidh, const ushort_t* hidl,
    const ushort_t* W2th, const ushort_t* W2tl,
    const float* b2, float* out) {
    GSHARED
    gtile<512, 512, 1024, 1024, 1024, 1, 1024, 1, 512, 1,0,1,0>(
        hidh, hidl, nullptr, nullptr, W2th, W2tl, nullptr, nullptr,
        b2, out, nullptr, nullptr, sAh, sAl, sBh, sBl);
}

// ================= fused attention over phi (single HBM pass) =================
__global__ __launch_bounds__(512) void phi_attn(
    const float* __restrict__ phi, const float* __restrict__ U,
    const float* __restrict__ po, const float* __restrict__ pi,
    float* __restrict__ v, ushort_t* __restrict__ wh, ushort_t* __restrict__ wl) {
    __shared__ float chunk[16 * 512];   // 32 KB (reused as exchange buffer)
    __shared__ float4 sco4[2][4], sci4[2][4];
    __shared__ float sred[8];
    const int b = blockIdx.x, tid = threadIdx.x;
    const int wave = tid >> 6, lane = tid & 63;
    const int cp = tid & 255, rh = tid >> 8;
    const float sc = 0.03125f * 1.4426950408889634f;  // 1/sqrt(dm) * log2(e)

    const float* uo = U + (size_t)b * 1024;
    const float* ui = uo + 512;
    float4 uo0 = ld4(uo + lane * 8), uo1 = ld4(uo + lane * 8 + 4);
    float4 ui0 = ld4(ui + lane * 8), ui1 = ld4(ui + lane * 8 + 4);
    const float* pb = phi + (size_t)b * NP * NA;

    float4 x00, x01, x10, x11;
    {
        const float* r0 = pb + (size_t)(wave * 2) * NA + lane * 8;
        x00 = ld4(r0); x01 = ld4(r0 + 4);
        x10 = ld4(r0 + NA); x11 = ld4(r0 + NA + 4);
    }

    float mo = -3.0e38f, mi = -3.0e38f;
    float Zo = 0.f, Zi = 0.f;
    float2 va = {0.f, 0.f}, Sa = {0.f, 0.f};

    for (int c = 0; c < 16; ++c) {
        const int p = c & 1;
        // ---- score 2 rows from regs ----
        {
            float d0a = uo0.x*x00.x + uo0.y*x00.y + uo0.z*x00.z + uo0.w*x00.w
                      + uo1.x*x01.x + uo1.y*x01.y + uo1.z*x01.z + uo1.w*x01.w;
            float d1a = ui0.x*x00.x + ui0.y*x00.y + ui0.z*x00.z + ui0.w*x00.w
                      + ui1.x*x01.x + ui1.y*x01.y + ui1.z*x01.z + ui1.w*x01.w;
            float d0b = uo0.x*x10.x + uo0.y*x10.y + uo0.z*x10.z + uo0.w*x10.w
                      + uo1.x*x11.x + uo1.y*x11.y + uo1.z*x11.z + uo1.w*x11.w;
            float d1b = ui0.x*x10.x + ui0.y*x10.y + ui0.z*x10.z + ui0.w*x10.w
                      + ui1.x*x11.x + ui1.y*x11.y + ui1.z*x11.z + ui1.w*x11.w;
            for (int off = 32; off; off >>= 1) {
                d0a += __shfl_xor(d0a, off); d1a += __shfl_xor(d1a, off);
                d0b += __shfl_xor(d0b, off); d1b += __shfl_xor(d1b, off);
            }
            if (lane == 0) {
                int n0 = c * 16 + wave * 2;
                float* so = reinterpret_cast<float*>(&sco4[p][0]);
                float* si = reinterpret_cast<float*>(&sci4[p][0]);
                so[wave*2]     = (d0a + po[b * NP + n0]) * sc;
                si[wave*2]     = (d1a + pi[b * 257 + n0 + 1]) * sc;
                so[wave*2 + 1] = (d0b + po[b * NP + n0 + 1]) * sc;
                si[wave*2 + 1] = (d1b + pi[b * 257 + n0 + 2]) * sc;
            }
        }
        __syncthreads();   // prev accumulate done; safe to overwrite chunk
        // ---- ds_write chunk ----
        {
            float* c0 = &chunk[(wave * 2) * 512 + lane * 8];
            *reinterpret_cast<float4*>(c0) = x00;
            *reinterpret_cast<float4*>(c0 + 4) = x01;
            *reinterpret_cast<float4*>(c0 + 512) = x10;
            *reinterpret_cast<float4*>(c0 + 516) = x11;
        }
        // ---- prefetch next chunk (in flight across barrier) ----
        if (c + 1 < 16) {
            const float* r0 = pb + (size_t)((c + 1) * 16 + wave * 2) * NA + lane * 8;
            x00 = ld4(r0); x01 = ld4(r0 + 4);
            x10 = ld4(r0 + NA); x11 = ld4(r0 + NA + 4);
        }
        __syncthreads();   // chunk + scores visible
        // ---- read scores as b128 broadcasts into regs ----
        float so[16], si[16];
        #pragma unroll
        for (int q = 0; q < 4; ++q) {
            float4 a = sco4[p][q];
            so[q*4] = a.x; so[q*4+1] = a.y; so[q*4+2] = a.z; so[q*4+3] = a.w;
            float4 e = sci4[p][q];
            si[q*4] = e.x; si[q*4+1] = e.y; si[q*4+2] = e.z; si[q*4+3] = e.w;
        }
        float nmo = mo, nmi = mi;
        #pragma unroll
        for (int n = 0; n < 16; ++n) {
            nmo = fmaxf(nmo, so[n]); nmi = fmaxf(nmi, si[n]);
        }
        float fo = exp2f(mo - nmo), fi = exp2f(mi - nmi);
        va.x *= fo; va.y *= fo; Zo *= fo;
        Sa.x *= fi; Sa.y *= fi; Zi *= fi;
        mo = nmo; mi = nmi;
        // ---- accumulate: 8 rows (this half) x 2 cols ----
        #pragma unroll
        for (int n = 0; n < 8; ++n) {
            int rr = rh * 8 + n;
            float e0 = exp2f(so[rr] - mo);
            float e1 = exp2f(si[rr] - mi);
            float2 x = *reinterpret_cast<float2*>(&chunk[rr * 512 + cp * 2]);
            va.x = fmaf(e0, x.x, va.x); va.y = fmaf(e0, x.y, va.y);
            Sa.x = fmaf(e1, x.x, Sa.x); Sa.y = fmaf(e1, x.y, Sa.y);
            Zo += e0; Zi += e1;
        }
    }

    // ---- combine row-halves via LDS exchange ----
    __syncthreads();
    float* fs = chunk;
    *reinterpret_cast<float2*>(&fs[2 * tid]) = va;
    *reinterpret_cast<float2*>(&fs[1024 + 2 * tid]) = Sa;
    fs[2048 + tid] = Zo; fs[3072 + tid] = Zi;
    __syncthreads();
    {
        float2 t1 = *reinterpret_cast<float2*>(&fs[2 * (tid ^ 256)]);
        va.x += t1.x; va.y += t1.y;
        float2 t2 = *reinterpret_cast<float2*>(&fs[1024 + 2 * (tid ^ 256)]);
        Sa.x += t2.x; Sa.y += t2.y;
        Zo += fs[2048 + (tid ^ 256)];
        Zi += fs[3072 + (tid ^ 256)];
    }

    float iZo = 1.0f / Zo;
    float2 v2 = {va.x * iZo, va.y * iZo};
    float2 ui2 = *reinterpret_cast<const float2*>(&ui[cp * 2]);
    float part = (rh == 0) ? (ui2.x * v2.x + ui2.y * v2.y) : 0.f;
    for (int off = 32; off; off >>= 1) part += __shfl_xor(part, off);
    if (lane == 0) sred[wave] = part;
    __syncthreads();
    float dot = ((sred[0] + sred[1]) + (sred[2] + sred[3]))
              + ((sred[4] + sred[5]) + (sred[6] + sred[7]));
    float s0 = (dot + pi[b * 257]) * sc;
    float e0 = exp2f(s0 - mi);
    float iZ = 1.0f / (Zi + e0);
    float wx = (e0 * v2.x + Sa.x) * iZ;
    float wy = (e0 * v2.y + Sa.y) * iZ;
    if (rh == 0) {
        *reinterpret_cast<float2*>(&v[(size_t)b * NA + cp * 2]) = v2;
        unsigned hx = bf16h(wx), hy = bf16h(wy);
        *reinterpret_cast<unsigned*>(wh + (size_t)b * NA + cp * 2) = hx | (hy << 16);
        unsigned lx = bf16h(wx - bf16f(hx)), ly = bf16h(wy - bf16f(hy));
        *reinterpret_cast<unsigned*>(wl + (size_t)b * NA + cp * 2) = lx | (ly << 16);
    }
}

// ---------------- final: out = softmax(v + logits) ----------------------------
__global__ __launch_bounds__(256) void final_softmax(const float* __restrict__ v,
                                                     float* __restrict__ out) {
    __shared__ float smem[4];
    int b = blockIdx.x, t = threadIdx.x;
    int lane = t & 63, w = t >> 6;
    float z0 = out[(size_t)b * NA + t] + v[(size_t)b * NA + t];
    float z1 = out[(size_t)b * NA + 256 + t] + v[(size_t)b * NA + 256 + t];
    float m = fmaxf(z0, z1);
    for (int off = 32; off; off >>= 1) m = fmaxf(m, __shfl_xor(m, off));
    __syncthreads();
    if (lane == 0) smem[w] = m;
    __syncthreads();
    m = fmaxf(fmaxf(smem[0], smem[1]), fmaxf(smem[2], smem[3]));
    float e0 = expf(z0 - m), e1 = expf(z1 - m);
    float s = e0 + e1;
    for (int off = 32; off; off >>= 1) s += __shfl_xor(s, off);
    __syncthreads();
    if (lane == 0) smem[w] = s;
    __syncthreads();
    float Z = (smem[0] + smem[1]) + (smem[2] + smem[3]);
    out[(size_t)b * NA + t] = e0 / Z;
    out[(size_t)b * NA + 256 + t] = e1 / Z;
}

// ---------------- launch ------------------------------------------------------
extern "C" void kernel_launch(void* const* d_in, const int* in_sizes, int n_in,
                              void* d_out, int out_size, void* d_ws, size_t ws_size,
                              hipStream_t stream) {
    const float* h_s = (const float*)d_in[0];
    const float* phi = (const float*)d_in[1];
    const float* WQo = (const float*)d_in[2];
    const float* WKo = (const float*)d_in[3];
    const float* WQi = (const float*)d_in[4];
    const float* WKi = (const float*)d_in[5];
    const float* WVi = (const float*)d_in[6];
    const float* W1  = (const float*)d_in[7];
    const float* b1  = (const float*)d_in[8];
    const float* W2  = (const float*)d_in[9];
    const float* b2  = (const float*)d_in[10];
    float* out = (float*)d_out;
    float* wsf = (float*)d_ws;

    size_t off = 0;
    auto af = [&](size_t n) { float* p = wsf + off; off += (n + 3) & ~(size_t)3; return p; };
    auto au = [&](size_t n) { ushort_t* p = (ushort_t*)(wsf + off); off += ((n / 2) + 3) & ~(size_t)3; return p; };

    ushort_t* peh   = au(257 * NA);          ushort_t* pel   = au(257 * NA);
    ushort_t* hsh   = au((size_t)BB*DE);     ushort_t* hsl   = au((size_t)BB*DE);
    ushort_t* WQoh  = au((size_t)DE*DM);     ushort_t* WQol  = au((size_t)DE*DM);
    ushort_t* WQih  = au((size_t)DE*DM);     ushort_t* WQil  = au((size_t)DE*DM);
    ushort_t* WKoh  = au((size_t)NA*DM);     ushort_t* WKol  = au((size_t)NA*DM);
    ushort_t* WKih  = au((size_t)NA*DM);     ushort_t* WKil  = au((size_t)NA*DM);
    ushort_t* WVih  = au((size_t)NA*DM);     ushort_t* WVil  = au((size_t)NA*DM);
    ushort_t* W1th  = au((size_t)DM*(DE+DM));ushort_t* W1tl  = au((size_t)DM*(DE+DM));
    ushort_t* W2th  = au((size_t)NA*DM);     ushort_t* W2tl  = au((size_t)NA*DM);
    ushort_t* Wbigh = au((size_t)1024*DE);   ushort_t* Wbigl = au((size_t)1024*DE);
    ushort_t* Wv1th = au((size_t)DM*NA);     ushort_t* Wv1tl = au((size_t)DM*NA);
    float*    Ubig  = af((size_t)BB * 1024);
    ushort_t* Ubigh = au((size_t)BB*1024);   ushort_t* Ubigl = au((size_t)BB*1024);
    float*    po    = af((size_t)BB * NP);
    float*    pi    = af((size_t)BB * 257);
    float*    v     = af((size_t)BB * NA);
    ushort_t* wh    = au((size_t)BB*NA);     ushort_t* wl    = au((size_t)BB*NA);
    ushort_t* hidh  = au((size_t)BB*DM);     ushort_t* hidl  = au((size_t)BB*DM);

    // 1. prep
    prep<<<6913, 256, 0, stream>>>(h_s, WQo, WQi, WKo, WKi, WVi, W1, W2,
                                   peh, pel, hsh, hsl,
                                   WQoh, WQol, WQih, WQil,
                                   WKoh, WKol, WKih, WKil,
                                   WVih, WVil, W1th, W1tl, W2th, W2tl);

    // 2. weight batch: Wc_out, Wc_in -> Wbig; Wv1t
    wbatch<<<dim3(16, 32, 3), 256, 0, stream>>>(
        WKoh, WKol, WKih, WKil, WQoh, WQol, WQih, WQil,
        W1th, W1tl, WVih, WVil, Wbigh, Wbigl, Wv1th, Wv1tl);

    // 3. U = h_s @ Wbig^T (cols 0-511 u_out, 512-1023 u_in)
    ugemm<<<dim3(16, 16), 256, 0, stream>>>(hsh, hsl, Wbigh, Wbigl,
                                            Ubig, Ubigh, Ubigl);

    // 4. pe dots
    pedots<<<dim3(5, 16, 2), 256, 0, stream>>>(Ubigh, Ubigl, peh, pel, po, pi);

    // 5. fused attention over phi -> v (fp32), w (hi/lo)
    phi_attn<<<BB, 512, 0, stream>>>(phi, Ubig, po, pi, v, wh, wl);

    // 6. hidden = relu([h_s|w] @ [W1a^T|Wv1t]^T + b1)
    hgemm<<<dim3(16, 16), 256, 0, stream>>>(hsh, hsl, wh, wl,
                                            W1th, W1tl, Wv1th, Wv1tl,
                                            b1, hidh, hidl);

    // 7. logits = hidden @ W2 + b2 -> out
    lgemm<<<dim3(8, 16), 256, 0, stream>>>(hidh, hidl, W2th, W2tl, b2, out);

    // 8. out = softmax(v + logits)
    final_softmax<<<BB, 256, 0, stream>>>(v, out);
}

// Round 7
// 130.114 us; speedup vs baseline: 2.2461x; 1.3142x over previous
//
#include <hip/hip_runtime.h>
#include <math.h>

// Problem dims
#define BB 512
#define DE 1024
#define DM 1024
#define NA 512
#define NP 256

typedef unsigned short ushort_t;
typedef __attribute__((ext_vector_type(8))) short s8v;   // 8 bf16 (4 VGPRs)
typedef __attribute__((ext_vector_type(4))) float f4v;   // 4 fp32 acc

static __device__ __forceinline__ float4 ld4(const float* p) {
    return *reinterpret_cast<const float4*>(p);
}
static __device__ __forceinline__ void ld8(const float* p, float* d) {
    float4 a = ld4(p), b = ld4(p + 4);
    d[0]=a.x; d[1]=a.y; d[2]=a.z; d[3]=a.w;
    d[4]=b.x; d[5]=b.y; d[6]=b.z; d[7]=b.w;
}

// RNE float -> bf16 bits
__device__ __forceinline__ unsigned bf16h(float x) {
    unsigned u = __float_as_uint(x);
    return (u + 0x7FFFu + ((u >> 16) & 1u)) >> 16;
}
__device__ __forceinline__ float bf16f(unsigned h) { return __uint_as_float(h << 16); }

__device__ __forceinline__ f4v mfma16(s8v a, s8v b, f4v c) {
    return __builtin_amdgcn_mfma_f32_16x16x32_bf16(a, b, c, 0, 0, 0);
}

// ================= PREP: PE table (fp32) + weight/h_s hi-lo splits ============
__device__ __forceinline__ void d_ew(const float* __restrict__ W,
                                     ushort_t* __restrict__ Hh,
                                     ushort_t* __restrict__ Hl, int bid) {
    int i = (bid * 256 + threadIdx.x) * 4;
    float4 f = ld4(W + i);
    float ff[4] = {f.x, f.y, f.z, f.w};
    unsigned h[4], l[4];
    #pragma unroll
    for (int q = 0; q < 4; ++q) { h[q] = bf16h(ff[q]); l[q] = bf16h(ff[q] - bf16f(h[q])); }
    *reinterpret_cast<uint2*>(Hh + i) = make_uint2(h[0] | (h[1] << 16), h[2] | (h[3] << 16));
    *reinterpret_cast<uint2*>(Hl + i) = make_uint2(l[0] | (l[1] << 16), l[2] | (l[3] << 16));
}

__device__ __forceinline__ void d_tr(const float* __restrict__ W,
                                     ushort_t* __restrict__ Th,
                                     ushort_t* __restrict__ Tl,
                                     int K, int N, int bid) {
    __shared__ float t[32][33];
    int ntn = N >> 5;
    int kt = bid / ntn, nt = bid - kt * ntn;
    int k0 = kt * 32, n0 = nt * 32;
    int ty = threadIdx.x >> 3, tx = (threadIdx.x & 7) * 4;
    float4 f = ld4(W + (size_t)(k0 + ty) * N + n0 + tx);
    t[ty][tx] = f.x; t[ty][tx + 1] = f.y; t[ty][tx + 2] = f.z; t[ty][tx + 3] = f.w;
    __syncthreads();
    unsigned h[4], l[4];
    #pragma unroll
    for (int q = 0; q < 4; ++q) {
        float x = t[tx + q][ty];
        h[q] = bf16h(x); l[q] = bf16h(x - bf16f(h[q]));
    }
    size_t o = (size_t)(n0 + ty) * K + k0 + tx;
    *reinterpret_cast<uint2*>(Th + o) = make_uint2(h[0] | (h[1] << 16), h[2] | (h[3] << 16));
    *reinterpret_cast<uint2*>(Tl + o) = make_uint2(l[0] | (l[1] << 16), l[2] | (l[3] << 16));
}

__global__ __launch_bounds__(256) void prep(
    const float* __restrict__ h_s, const float* __restrict__ WQo,
    const float* __restrict__ WQi, const float* __restrict__ WKo,
    const float* __restrict__ WKi, const float* __restrict__ WVi,
    const float* __restrict__ W1, const float* __restrict__ W2,
    float* pef, ushort_t* hsh, ushort_t* hsl,
    ushort_t* WQoh, ushort_t* WQol, ushort_t* WQih, ushort_t* WQil,
    ushort_t* WKoh, ushort_t* WKol, ushort_t* WKih, ushort_t* WKil,
    ushort_t* WVih, ushort_t* WVil, ushort_t* W1th, ushort_t* W1tl,
    ushort_t* W2th, ushort_t* W2tl) {
    int bid = blockIdx.x;
    if (bid < 257) {
        int p = bid, i = threadIdx.x;
        const float c = -0.017988946039015984f; // -ln(10000)/512
        float div = expf((float)(2 * i) * c);
        float arg = (float)p * div;
        float2 scv = make_float2(sinf(arg), cosf(arg));
        *reinterpret_cast<float2*>(pef + p * NA + 2 * i) = scv;
        return;
    }
    if ((bid -= 257) < 512)  { d_ew(h_s, hsh, hsl, bid); return; }
    if ((bid -= 512) < 1024) { d_ew(WQo, WQoh, WQol, bid); return; }
    if ((bid -= 1024) < 1024){ d_ew(WQi, WQih, WQil, bid); return; }
    if ((bid -= 1024) < 512) { d_ew(WKo, WKoh, WKol, bid); return; }
    if ((bid -= 512) < 512)  { d_ew(WKi, WKih, WKil, bid); return; }
    if ((bid -= 512) < 512)  { d_ew(WVi, WVih, WVil, bid); return; }
    if ((bid -= 512) < 2048) { d_tr(W1, W1th, W1tl, DE + DM, DM, bid); return; }
    bid -= 2048;               d_tr(W2, W2th, W2tl, DM, NA, bid);
}

// ================= split-bf16 MFMA GEMM tile (all-static dims) ================
// C[M,N] = (Ah+Al)[M,K] @ (Bh+Bl)[N,K]^T, 3-product split, fp32 accum.
// 32x64 tile, 4 waves, static double-buffered LDS, ONE barrier per K-tile,
// next tile's global loads issued before the barrier. Fully unrolled (K static).
// Concat: k >= KS reads A2 (stride LDA2) / B2 (stride LDB2).
template<int M, int N, int K, int KS, int LDA, int LDA2, int LDB, int LDB2,
         int LDC, int BIAS, int RELU, int CFOUT, int CHOUT>
__device__ __forceinline__ void gtile(
    const ushort_t* __restrict__ Ah, const ushort_t* __restrict__ Al,
    const ushort_t* __restrict__ A2h, const ushort_t* __restrict__ A2l,
    const ushort_t* __restrict__ Bh, const ushort_t* __restrict__ Bl,
    const ushort_t* __restrict__ B2h, const ushort_t* __restrict__ B2l,
    const float* __restrict__ bias, float* __restrict__ Cf,
    ushort_t* __restrict__ Ch, ushort_t* __restrict__ Cl,
    ushort_t* sAh, ushort_t* sAl, ushort_t* sBh, ushort_t* sBl) {
    const int row0 = blockIdx.y * 32, col0 = blockIdx.x * 64;
    if (row0 >= M || col0 >= N) return;
    const int tid = threadIdx.x;

    const int ar = tid >> 3, ak = (tid & 7) * 8;
    const int asi = ar * 64 + (ak ^ ((ar & 7) << 3));
    const int br = tid >> 2, bk = (tid & 3) * 16;
    const int bsw = (br & 7) << 3;
    const int bsi0 = br * 64 + (bk ^ bsw);
    const int bsi1 = br * 64 + ((bk + 8) ^ bsw);

    const int wid = tid >> 6, lane = tid & 63;
    const int wm = wid & 1, wn = wid >> 1;
    const int lm = lane & 15, lk = lane >> 4;
    const int ra = wm * 16 + lm;
    const int rb = wn * 32 + lm;
    const int aswz = (ra & 7) << 3;
    const int bswz = (rb & 7) << 3;

    const int nb = col0 + br;
    const bool bval = (N % 64 == 0) || (nb < N);

    int4 rah, ral, rb0h, rb1h, rb0l, rb1l;
    auto load = [&](int k0) {
        if (KS < K && k0 >= KS) {
            size_t ao = (size_t)(row0 + ar) * LDA2 + (k0 - KS) + ak;
            rah = *reinterpret_cast<const int4*>(A2h + ao);
            ral = *reinterpret_cast<const int4*>(A2l + ao);
        } else {
            size_t ao = (size_t)(row0 + ar) * LDA + k0 + ak;
            rah = *reinterpret_cast<const int4*>(Ah + ao);
            ral = *reinterpret_cast<const int4*>(Al + ao);
        }
        if (bval) {
            if (KS < K && k0 >= KS) {
                size_t bo = (size_t)nb * LDB2 + (k0 - KS) + bk;
                rb0h = *reinterpret_cast<const int4*>(B2h + bo);
                rb1h = *reinterpret_cast<const int4*>(B2h + bo + 8);
                rb0l = *reinterpret_cast<const int4*>(B2l + bo);
                rb1l = *reinterpret_cast<const int4*>(B2l + bo + 8);
            } else {
                size_t bo = (size_t)nb * LDB + k0 + bk;
                rb0h = *reinterpret_cast<const int4*>(Bh + bo);
                rb1h = *reinterpret_cast<const int4*>(Bh + bo + 8);
                rb0l = *reinterpret_cast<const int4*>(Bl + bo);
                rb1l = *reinterpret_cast<const int4*>(Bl + bo + 8);
            }
        } else {
            rb0h = make_int4(0,0,0,0); rb1h = make_int4(0,0,0,0);
            rb0l = make_int4(0,0,0,0); rb1l = make_int4(0,0,0,0);
        }
    };

    f4v acc[2] = {};
    load(0);
    constexpr int NT = K >> 6;
    #pragma unroll
    for (int t = 0; t < NT; ++t) {
        const int co = (t & 1) ? 2048 : 0;
        const int cb = (t & 1) ? 4096 : 0;
        *reinterpret_cast<int4*>(&sAh[co + asi]) = rah;
        *reinterpret_cast<int4*>(&sAl[co + asi]) = ral;
        *reinterpret_cast<int4*>(&sBh[cb + bsi0]) = rb0h;
        *reinterpret_cast<int4*>(&sBh[cb + bsi1]) = rb1h;
        *reinterpret_cast<int4*>(&sBl[cb + bsi0]) = rb0l;
        *reinterpret_cast<int4*>(&sBl[cb + bsi1]) = rb1l;
        if (t + 1 < NT) load((t + 1) << 6);
        __syncthreads();
        #pragma unroll
        for (int ks = 0; ks < 2; ++ks) {
            const int ka = (ks * 32 + lk * 8) ^ aswz;
            const int kb = (ks * 32 + lk * 8) ^ bswz;
            s8v a_h = *reinterpret_cast<const s8v*>(&sAh[co + ra * 64 + ka]);
            s8v a_l = *reinterpret_cast<const s8v*>(&sAl[co + ra * 64 + ka]);
            s8v b0h = *reinterpret_cast<const s8v*>(&sBh[cb + rb * 64 + kb]);
            s8v b1h = *reinterpret_cast<const s8v*>(&sBh[cb + (rb + 16) * 64 + kb]);
            s8v b0l = *reinterpret_cast<const s8v*>(&sBl[cb + rb * 64 + kb]);
            s8v b1l = *reinterpret_cast<const s8v*>(&sBl[cb + (rb + 16) * 64 + kb]);
            acc[0] = mfma16(a_h, b0h, acc[0]);
            acc[1] = mfma16(a_h, b1h, acc[1]);
            acc[0] = mfma16(a_h, b0l, acc[0]);
            acc[1] = mfma16(a_h, b1l, acc[1]);
            acc[0] = mfma16(a_l, b0h, acc[0]);
            acc[1] = mfma16(a_l, b1h, acc[1]);
        }
    }

    #pragma unroll
    for (int j = 0; j < 2; ++j) {
        int gc = col0 + wn * 32 + j * 16 + lm;
        if (N % 64 != 0 && gc >= N) continue;
        float bv = BIAS ? bias[gc] : 0.0f;
        #pragma unroll
        for (int r = 0; r < 4; ++r) {
            int gr = row0 + wm * 16 + lk * 4 + r;
            float val = acc[j][r] + bv;
            if (RELU) val = fmaxf(val, 0.0f);
            size_t o = (size_t)gr * LDC + gc;
            if (CFOUT) Cf[o] = val;
            if (CHOUT) {
                unsigned h = bf16h(val);
                Ch[o] = (ushort_t)h;
                Cl[o] = (ushort_t)bf16h(val - bf16f(h));
            }
        }
    }
}

#define GSHARED \
    __shared__ ushort_t sAh[2 * 2048], sAl[2 * 2048]; \
    __shared__ ushort_t sBh[2 * 4096], sBl[2 * 4096];

// ---- weight batch: z0/z1: Wc = WK @ WQ^T (512x1024x1024); z2: Wv1t ----------
__global__ __launch_bounds__(256) void wbatch(
    const ushort_t* WKoh, const ushort_t* WKol,
    const ushort_t* WKih, const ushort_t* WKil,
    const ushort_t* WQoh, const ushort_t* WQol,
    const ushort_t* WQih, const ushort_t* WQil,
    const ushort_t* W1th, const ushort_t* W1tl,
    const ushort_t* WVih, const ushort_t* WVil,
    ushort_t* Wbigh, ushort_t* Wbigl,
    ushort_t* Wv1th, ushort_t* Wv1tl) {
    GSHARED
    const int z = blockIdx.z;
    if (z == 2) {
        // Wv1t[n][a] = sum_d W1b[d][n] * WVi[a][d]  (M=1024,N=512,K=1024)
        gtile<1024, 512, 1024, 1024, 2048, 1, 1024, 1, 512, 0,0,0,1>(
            W1th + 1024, W1tl + 1024, nullptr, nullptr,
            WVih, WVil, nullptr, nullptr,
            nullptr, nullptr, Wv1th, Wv1tl, sAh, sAl, sBh, sBl);
    } else {
        const ushort_t* Ah = z ? WKih : WKoh;
        const ushort_t* Al = z ? WKil : WKol;
        const ushort_t* Bh = z ? WQih : WQoh;
        const ushort_t* Bl = z ? WQil : WQol;
        ushort_t* Ch = Wbigh + (size_t)z * 512 * 1024;
        ushort_t* Cl = Wbigl + (size_t)z * 512 * 1024;
        gtile<512, 1024, 1024, 1024, 1024, 1, 1024, 1, 1024, 0,0,0,1>(
            Ah, Al, nullptr, nullptr, Bh, Bl, nullptr, nullptr,
            nullptr, nullptr, Ch, Cl, sAh, sAl, sBh, sBl);
    }
}

// ---- U = h_s @ Wbig^T (512x1024x1024), fp32 only -----------------------------
__global__ __launch_bounds__(256) void ugemm(
    const ushort_t* hsh, const ushort_t* hsl,
    const ushort_t* Wbigh, const ushort_t* Wbigl,
    float* Ubig) {
    GSHARED
    gtile<512, 1024, 1024, 1024, 1024, 1, 1024, 1, 1024, 0,0,1,0>(
        hsh, hsl, nullptr, nullptr, Wbigh, Wbigl, nullptr, nullptr,
        nullptr, Ubig, nullptr, nullptr, sAh, sAl, sBh, sBl);
}

// ---- hidden = relu([h_s|w] @ [W1a^T|Wv1t]^T + b1) (512x1024x1536) ------------
__global__ __launch_bounds__(256) void hgemm(
    const ushort_t* hsh, const ushort_t* hsl,
    const ushort_t* wh, const ushort_t* wl,
    const ushort_t* W1th, const ushort_t* W1tl,
    const ushort_t* Wv1th, const ushort_t* Wv1tl,
    const float* b1, ushort_t* hidh, ushort_t* hidl) {
    GSHARED
    gtile<512, 1024, 1536, 1024, 1024, 512, 2048, 512, 1024, 1,1,0,1>(
        hsh, hsl, wh, wl, W1th, W1tl, Wv1th, Wv1tl,
        b1, nullptr, hidh, hidl, sAh, sAl, sBh, sBl);
}

// ---- logits = hidden @ W2 + b2 (512x512x1024) -> out -------------------------
__global__ __launch_bounds__(256) void lgemm(
    const ushort_t* hidh, const ushort_t* hidl,
    const ushort_t* W2th, const ushort_t* W2tl,
    const float* b2, float* out) {
    GSHARED
    gtile<512, 512, 1024, 1024, 1024, 1, 1024, 1, 512, 1,0,1,0>(
        hidh, hidl, nullptr, nullptr, W2th, W2tl, nullptr, nullptr,
        b2, out, nullptr, nullptr, sAh, sAl, sBh, sBl);
}

// ================= fused attention over phi (barrier-free stream) =============
// 512 threads = 8 waves per block, one block per b. Wave w owns rows
// {c*16 + w*2, +1} of each 16-row chunk with its OWN online-softmax state
// (wave-uniform after butterfly reduce -> no cross-wave sync in the loop).
// Each thread accumulates its 8 columns straight from the load registers
// (no LDS chunk). PE dots are folded inline: s = u.(phi[n]+pe[n']) * sc.
// Flash-style 8-way merge at the end.
__global__ __launch_bounds__(512) void phi_attn(
    const float* __restrict__ phi, const float* __restrict__ U,
    const float* __restrict__ pe, float* __restrict__ v,
    ushort_t* __restrict__ wh, ushort_t* __restrict__ wl) {
    __shared__ float sva[8][512];   // 16 KB
    __shared__ float ssa[8][512];   // 16 KB
    __shared__ float smx[4][8];
    __shared__ float sred[8];
    const int b = blockIdx.x, tid = threadIdx.x;
    const int wave = tid >> 6, lane = tid & 63;
    const float sc = 0.03125f * 1.4426950408889634f;  // 1/sqrt(dm) * log2(e)

    const float* ub = U + (size_t)b * 1024;
    float u8o[8], u8i[8];
    ld8(ub + lane * 8, u8o);
    ld8(ub + 512 + lane * 8, u8i);
    const float* pb = phi + (size_t)b * NP * NA;

    float x0[8], x1[8];
    {
        const float* r = pb + (size_t)(wave * 2) * NA + lane * 8;
        ld8(r, x0); ld8(r + NA, x1);
    }

    float mo = -3.0e38f, mi = -3.0e38f, Zo = 0.f, Zi = 0.f;
    float va[8] = {}, Sa[8] = {};

    for (int c = 0; c < 16; ++c) {
        const int r0 = c * 16 + wave * 2;
        float p0[8], p1[8], p2[8];
        ld8(pe + (size_t)r0 * NA + lane * 8, p0);
        ld8(pe + (size_t)(r0 + 1) * NA + lane * 8, p1);
        ld8(pe + (size_t)(r0 + 2) * NA + lane * 8, p2);
        float so0 = 0.f, si0 = 0.f, so1 = 0.f, si1 = 0.f;
        #pragma unroll
        for (int j = 0; j < 8; ++j) {
            so0 = fmaf(u8o[j], x0[j] + p0[j], so0);
            si0 = fmaf(u8i[j], x0[j] + p1[j], si0);
            so1 = fmaf(u8o[j], x1[j] + p1[j], so1);
            si1 = fmaf(u8i[j], x1[j] + p2[j], si1);
        }
        for (int off = 32; off; off >>= 1) {
            so0 += __shfl_xor(so0, off); si0 += __shfl_xor(si0, off);
            so1 += __shfl_xor(so1, off); si1 += __shfl_xor(si1, off);
        }
        so0 *= sc; si0 *= sc; so1 *= sc; si1 *= sc;
        // prefetch next chunk rows (in flight under the exp/accumulate VALU)
        float n0[8], n1[8];
        if (c < 15) {
            const float* r = pb + (size_t)((c + 1) * 16 + wave * 2) * NA + lane * 8;
            ld8(r, n0); ld8(r + NA, n1);
        }
        float nmo = fmaxf(mo, fmaxf(so0, so1));
        float nmi = fmaxf(mi, fmaxf(si0, si1));
        float fo = exp2f(mo - nmo), fi = exp2f(mi - nmi);
        float e00 = exp2f(so0 - nmo), e01 = exp2f(so1 - nmo);
        float e10 = exp2f(si0 - nmi), e11 = exp2f(si1 - nmi);
        mo = nmo; mi = nmi;
        Zo = Zo * fo + (e00 + e01);
        Zi = Zi * fi + (e10 + e11);
        #pragma unroll
        for (int j = 0; j < 8; ++j) {
            va[j] = fmaf(va[j], fo, fmaf(e00, x0[j], e01 * x1[j]));
            Sa[j] = fmaf(Sa[j], fi, fmaf(e10, x0[j], e11 * x1[j]));
        }
        if (c < 15) {
            #pragma unroll
            for (int j = 0; j < 8; ++j) { x0[j] = n0[j]; x1[j] = n1[j]; }
        }
    }

    // ---- flash merge across the 8 waves ----
    if (lane == 0) { smx[0][wave] = mo; smx[1][wave] = mi; }
    __syncthreads();
    float gmo = smx[0][0], gmi = smx[1][0];
    #pragma unroll
    for (int w2 = 1; w2 < 8; ++w2) {
        gmo = fmaxf(gmo, smx[0][w2]); gmi = fmaxf(gmi, smx[1][w2]);
    }
    float fo = exp2f(mo - gmo), fi = exp2f(mi - gmi);
    {
        float4 a0 = {va[0]*fo, va[1]*fo, va[2]*fo, va[3]*fo};
        float4 a1 = {va[4]*fo, va[5]*fo, va[6]*fo, va[7]*fo};
        *reinterpret_cast<float4*>(&sva[wave][lane * 8]) = a0;
        *reinterpret_cast<float4*>(&sva[wave][lane * 8 + 4]) = a1;
        float4 s0v = {Sa[0]*fi, Sa[1]*fi, Sa[2]*fi, Sa[3]*fi};
        float4 s1v = {Sa[4]*fi, Sa[5]*fi, Sa[6]*fi, Sa[7]*fi};
        *reinterpret_cast<float4*>(&ssa[wave][lane * 8]) = s0v;
        *reinterpret_cast<float4*>(&ssa[wave][lane * 8 + 4]) = s1v;
    }
    if (lane == 0) { smx[2][wave] = Zo * fo; smx[3][wave] = Zi * fi; }
    __syncthreads();
    float Zot = 0.f, Zit = 0.f;
    #pragma unroll
    for (int w2 = 0; w2 < 8; ++w2) { Zot += smx[2][w2]; Zit += smx[3][w2]; }
    float vs = 0.f, Ss = 0.f;
    #pragma unroll
    for (int w2 = 0; w2 < 8; ++w2) { vs += sva[w2][tid]; Ss += ssa[w2][tid]; }
    float vt = vs / Zot;
    v[(size_t)b * NA + tid] = vt;

    // ---- in-head row-0 fixup -> w ----
    float uit = U[(size_t)b * 1024 + 512 + tid];
    float part = uit * (vt + pe[tid]);   // pe row 0
    for (int off = 32; off; off >>= 1) part += __shfl_xor(part, off);
    if (lane == 0) sred[wave] = part;
    __syncthreads();
    float dot = ((sred[0] + sred[1]) + (sred[2] + sred[3]))
              + ((sred[4] + sred[5]) + (sred[6] + sred[7]));
    float s0 = dot * sc;
    float e0 = exp2f(s0 - gmi);
    float iZ = 1.0f / (Zit + e0);
    float wt = (e0 * vt + Ss) * iZ;
    unsigned h = bf16h(wt);
    wh[(size_t)b * NA + tid] = (ushort_t)h;
    wl[(size_t)b * NA + tid] = (ushort_t)bf16h(wt - bf16f(h));
}

// ---------------- final: out = softmax(v + logits) ----------------------------
__global__ __launch_bounds__(256) void final_softmax(const float* __restrict__ v,
                                                     float* __restrict__ out) {
    __shared__ float smem[4];
    int b = blockIdx.x, t = threadIdx.x;
    int lane = t & 63, w = t >> 6;
    float z0 = out[(size_t)b * NA + t] + v[(size_t)b * NA + t];
    float z1 = out[(size_t)b * NA + 256 + t] + v[(size_t)b * NA + 256 + t];
    float m = fmaxf(z0, z1);
    for (int off = 32; off; off >>= 1) m = fmaxf(m, __shfl_xor(m, off));
    __syncthreads();
    if (lane == 0) smem[w] = m;
    __syncthreads();
    m = fmaxf(fmaxf(smem[0], smem[1]), fmaxf(smem[2], smem[3]));
    float e0 = expf(z0 - m), e1 = expf(z1 - m);
    float s = e0 + e1;
    for (int off = 32; off; off >>= 1) s += __shfl_xor(s, off);
    __syncthreads();
    if (lane == 0) smem[w] = s;
    __syncthreads();
    float Z = (smem[0] + smem[1]) + (smem[2] + smem[3]);
    out[(size_t)b * NA + t] = e0 / Z;
    out[(size_t)b * NA + 256 + t] = e1 / Z;
}

// ---------------- launch ------------------------------------------------------
extern "C" void kernel_launch(void* const* d_in, const int* in_sizes, int n_in,
                              void* d_out, int out_size, void* d_ws, size_t ws_size,
                              hipStream_t stream) {
    const float* h_s = (const float*)d_in[0];
    const float* phi = (const float*)d_in[1];
    const float* WQo = (const float*)d_in[2];
    const float* WKo = (const float*)d_in[3];
    const float* WQi = (const float*)d_in[4];
    const float* WKi = (const float*)d_in[5];
    const float* WVi = (const float*)d_in[6];
    const float* W1  = (const float*)d_in[7];
    const float* b1  = (const float*)d_in[8];
    const float* W2  = (const float*)d_in[9];
    const float* b2  = (const float*)d_in[10];
    float* out = (float*)d_out;
    float* wsf = (float*)d_ws;

    size_t off = 0;
    auto af = [&](size_t n) { float* p = wsf + off; off += (n + 3) & ~(size_t)3; return p; };
    auto au = [&](size_t n) { ushort_t* p = (ushort_t*)(wsf + off); off += ((n / 2) + 3) & ~(size_t)3; return p; };

    float*    pef   = af(257 * NA);
    ushort_t* hsh   = au((size_t)BB*DE);     ushort_t* hsl   = au((size_t)BB*DE);
    ushort_t* WQoh  = au((size_t)DE*DM);     ushort_t* WQol  = au((size_t)DE*DM);
    ushort_t* WQih  = au((size_t)DE*DM);     ushort_t* WQil  = au((size_t)DE*DM);
    ushort_t* WKoh  = au((size_t)NA*DM);     ushort_t* WKol  = au((size_t)NA*DM);
    ushort_t* WKih  = au((size_t)NA*DM);     ushort_t* WKil  = au((size_t)NA*DM);
    ushort_t* WVih  = au((size_t)NA*DM);     ushort_t* WVil  = au((size_t)NA*DM);
    ushort_t* W1th  = au((size_t)DM*(DE+DM));ushort_t* W1tl  = au((size_t)DM*(DE+DM));
    ushort_t* W2th  = au((size_t)NA*DM);     ushort_t* W2tl  = au((size_t)NA*DM);
    ushort_t* Wbigh = au((size_t)1024*DE);   ushort_t* Wbigl = au((size_t)1024*DE);
    ushort_t* Wv1th = au((size_t)DM*NA);     ushort_t* Wv1tl = au((size_t)DM*NA);
    float*    Ubig  = af((size_t)BB * 1024);
    float*    v     = af((size_t)BB * NA);
    ushort_t* wh    = au((size_t)BB*NA);     ushort_t* wl    = au((size_t)BB*NA);
    ushort_t* hidh  = au((size_t)BB*DM);     ushort_t* hidl  = au((size_t)BB*DM);

    // 1. prep
    prep<<<6913, 256, 0, stream>>>(h_s, WQo, WQi, WKo, WKi, WVi, W1, W2,
                                   pef, hsh, hsl,
                                   WQoh, WQol, WQih, WQil,
                                   WKoh, WKol, WKih, WKil,
                                   WVih, WVil, W1th, W1tl, W2th, W2tl);

    // 2. weight batch: Wc_out, Wc_in -> Wbig; Wv1t
    wbatch<<<dim3(16, 32, 3), 256, 0, stream>>>(
        WKoh, WKol, WKih, WKil, WQoh, WQol, WQih, WQil,
        W1th, W1tl, WVih, WVil, Wbigh, Wbigl, Wv1th, Wv1tl);

    // 3. U = h_s @ Wbig^T (cols 0-511 u_out, 512-1023 u_in)
    ugemm<<<dim3(16, 16), 256, 0, stream>>>(hsh, hsl, Wbigh, Wbigl, Ubig);

    // 4. fused attention over phi (inline pe dots) -> v (fp32), w (hi/lo)
    phi_attn<<<BB, 512, 0, stream>>>(phi, Ubig, pef, v, wh, wl);

    // 5. hidden = relu([h_s|w] @ [W1a^T|Wv1t]^T + b1)
    hgemm<<<dim3(16, 16), 256, 0, stream>>>(hsh, hsl, wh, wl,
                                            W1th, W1tl, Wv1th, Wv1tl,
                                            b1, hidh, hidl);

    // 6. logits = hidden @ W2 + b2 -> out
    lgemm<<<dim3(8, 16), 256, 0, stream>>>(hidh, hidl, W2th, W2tl, b2, out);

    // 7. out = softmax(v + logits)
    final_softmax<<<BB, 256, 0, stream>>>(v, out);
}